// Round 1
// baseline (216.427 us; speedup 1.0000x reference)
//
#include <hip/hip_runtime.h>

typedef short short8 __attribute__((ext_vector_type(8)));
typedef __bf16 bf16x8 __attribute__((ext_vector_type(8)));
typedef float f32x4 __attribute__((ext_vector_type(4)));

#define NFEAT 1024
#define HDIM  64
#define NHEAD 16
#define TC2   2048   // total kv positions after concat

__device__ __forceinline__ short f2bf(float f) {
    unsigned int u = __builtin_bit_cast(unsigned int, f);
    u += 0x7fffu + ((u >> 16) & 1u);          // round-to-nearest-even
    return (short)(u >> 16);
}

__device__ __forceinline__ f32x4 mfma_bf16(short8 a, short8 b, f32x4 c) {
    return __builtin_amdgcn_mfma_f32_16x16x32_bf16(
        __builtin_bit_cast(bf16x8, a), __builtin_bit_cast(bf16x8, b), c, 0, 0, 0);
}

// ---------------------------------------------------------------------------
// Copy fp32 cache -> new_cache[:, :, :1024, :]; also emit bf16 K [BH,2048,64]
// (first 1024 rows) and bf16 V^T [BH,64,2048] (first 1024 cols).
// ---------------------------------------------------------------------------
__global__ __launch_bounds__(256) void cache_prep(
    const float4* __restrict__ cache4, float4* __restrict__ nc4,
    short* __restrict__ kb, short* __restrict__ vtb)
{
    int i = blockIdx.x * blockDim.x + threadIdx.x;     // over 2*16*1024*32 float4
    if (i >= 2 * 16 * 1024 * 32) return;
    int c4 = i & 31;
    int t  = (i >> 5) & 1023;
    int bh = i >> 15;
    float4 v = cache4[i];
    nc4[((size_t)bh * TC2 + t) * 32 + c4] = v;
    int c = c4 * 4;
    if (c < 64) {
        size_t base = ((size_t)bh * TC2 + t) * HDIM + c;
        kb[base + 0] = f2bf(v.x); kb[base + 1] = f2bf(v.y);
        kb[base + 2] = f2bf(v.z); kb[base + 3] = f2bf(v.w);
    } else {
        int d = c - 64;
        size_t base = ((size_t)bh * HDIM + d) * TC2 + t;
        vtb[base + 0 * TC2] = f2bf(v.x); vtb[base + 1 * TC2] = f2bf(v.y);
        vtb[base + 2 * TC2] = f2bf(v.z); vtb[base + 3 * TC2] = f2bf(v.w);
    }
}

// ---------------------------------------------------------------------------
// GEMM  y[m][n] = sum_k A[m][k] * W[n][k] + bias[n]
// BM=BN=64, BK=32, 256 threads (4 waves, 2x2), wave tile 32x32.
// MODE: 0 = fp32 out [M][N] (final proj)
//       1 = Q  -> bf16 q_buf  [B,H,1024,64]
//       2 = K  -> fp32 new_cache[...,:64]   + bf16 kb [BH,2048,64]
//       3 = V  -> fp32 new_cache[...,64:]   + bf16 vt [BH,64,2048]
// ---------------------------------------------------------------------------
template <int MODE, bool ABF16>
__global__ __launch_bounds__(256) void gemm_bt(
    const void* __restrict__ Ap, const float* __restrict__ Bw,
    const float* __restrict__ bias,
    float* __restrict__ outf, short* __restrict__ outb, short* __restrict__ vtb,
    int M, int N, int K)
{
    __shared__ short As[64 * 40];
    __shared__ short Bs[64 * 40];

    const int tid = threadIdx.x;
    const int lane = tid & 63, w = tid >> 6;
    const int wr = w >> 1, wc = w & 1;
    const int lr = lane & 15, lg = lane >> 4;
    const int bx = blockIdx.x, by = blockIdx.y;
    const int srow = tid >> 2, sc8 = (tid & 3) * 8;

    f32x4 acc[2][2];
#pragma unroll
    for (int m = 0; m < 2; ++m)
#pragma unroll
        for (int n = 0; n < 2; ++n) acc[m][n] = (f32x4){0.f, 0.f, 0.f, 0.f};

    const int nkt = K >> 5;
    for (int kt = 0; kt < nkt; ++kt) {
        // ---- stage A tile [64][32] ----
        {
            int gr = by * 64 + srow;
            int gc = kt * 32 + sc8;
            short8 v;
            if (ABF16) {
                v = *(const short8*)((const short*)Ap + (size_t)gr * K + gc);
            } else {
                const float* ap = (const float*)Ap + (size_t)gr * K + gc;
#pragma unroll
                for (int j = 0; j < 8; ++j) v[j] = f2bf(ap[j]);
            }
            *(short8*)&As[srow * 40 + sc8] = v;
            // ---- stage B tile (rows = output cols) ----
            const float* bp = Bw + (size_t)(bx * 64 + srow) * K + gc;
            short8 u;
#pragma unroll
            for (int j = 0; j < 8; ++j) u[j] = f2bf(bp[j]);
            *(short8*)&Bs[srow * 40 + sc8] = u;
        }
        __syncthreads();
        short8 af[2], bfr[2];
#pragma unroll
        for (int m = 0; m < 2; ++m)
            af[m] = *(const short8*)&As[(wr * 32 + m * 16 + lr) * 40 + lg * 8];
#pragma unroll
        for (int n = 0; n < 2; ++n)
            bfr[n] = *(const short8*)&Bs[(wc * 32 + n * 16 + lr) * 40 + lg * 8];
#pragma unroll
        for (int m = 0; m < 2; ++m)
#pragma unroll
            for (int n = 0; n < 2; ++n)
                acc[m][n] = mfma_bf16(af[m], bfr[n], acc[m][n]);
        __syncthreads();
    }

    // ---- epilogue ----
#pragma unroll
    for (int m = 0; m < 2; ++m) {
#pragma unroll
        for (int n = 0; n < 2; ++n) {
#pragma unroll
            for (int r = 0; r < 4; ++r) {
                int rg = by * 64 + wr * 32 + m * 16 + lg * 4 + r;
                int cg = bx * 64 + wc * 32 + n * 16 + lr;
                float val = acc[m][n][r] + bias[cg];
                if (MODE == 0) {
                    outf[(size_t)rg * N + cg] = val;
                } else {
                    int b = rg >> 10, t = rg & 1023;
                    int h = cg >> 6, d = cg & 63;
                    size_t bh = (size_t)b * NHEAD + h;
                    if (MODE == 1) {
                        outb[(bh * 1024 + t) * HDIM + d] = f2bf(val);
                    } else if (MODE == 2) {
                        outf[(bh * TC2 + 1024 + t) * 128 + d] = val;
                        outb[(bh * TC2 + 1024 + t) * HDIM + d] = f2bf(val);
                    } else {
                        outf[(bh * TC2 + 1024 + t) * 128 + 64 + d] = val;
                        vtb[(bh * HDIM + d) * TC2 + 1024 + t] = f2bf(val);
                    }
                }
            }
        }
    }
}

// ---------------------------------------------------------------------------
// Flash attention: one block = (bh, q-tile of 64). 4 waves, each owns 16 q rows.
// KVBLK=64. K tile [64][64] and V^T tile [64][64] staged in padded LDS (bf16).
// ---------------------------------------------------------------------------
__global__ __launch_bounds__(256) void attn_kernel(
    const short* __restrict__ qb, const short* __restrict__ kb,
    const short* __restrict__ vtb, short* __restrict__ xb)
{
    __shared__ short Ks[64 * 72];
    __shared__ short Vs[64 * 72];
    __shared__ short Ps[4 * 16 * 72];

    const int tid = threadIdx.x, lane = tid & 63, w = tid >> 6;
    const int lr = lane & 15, lg = lane >> 4;
    const int bh = blockIdx.x >> 4, qt = blockIdx.x & 15;

    // Q fragments (hoisted): rows w*16+lr of this q-tile
    const short* qrow = qb + ((size_t)bh * 1024 + qt * 64 + w * 16 + lr) * HDIM;
    short8 aq0 = *(const short8*)(qrow + lg * 8);
    short8 aq1 = *(const short8*)(qrow + 32 + lg * 8);

    f32x4 accx[4];
#pragma unroll
    for (int i = 0; i < 4; ++i) accx[i] = (f32x4){0.f, 0.f, 0.f, 0.f};
    float ms[4], ls[4];
#pragma unroll
    for (int r = 0; r < 4; ++r) { ms[r] = -3.0e38f; ls[r] = 0.f; }

    const int srow = tid >> 2, sc = (tid & 3) * 16;
    short* pw = &Ps[w * 16 * 72];

    for (int kvt = 0; kvt < TC2 / 64; ++kvt) {
        // ---- stage K and V^T tiles ----
        {
            const short* kg = kb + ((size_t)bh * TC2 + kvt * 64 + srow) * HDIM + sc;
            short8 k0 = *(const short8*)kg;
            short8 k1 = *(const short8*)(kg + 8);
            *(short8*)&Ks[srow * 72 + sc]     = k0;
            *(short8*)&Ks[srow * 72 + sc + 8] = k1;
            const short* vg = vtb + ((size_t)bh * HDIM + srow) * TC2 + kvt * 64 + sc;
            short8 v0 = *(const short8*)vg;
            short8 v1 = *(const short8*)(vg + 8);
            *(short8*)&Vs[srow * 72 + sc]     = v0;
            *(short8*)&Vs[srow * 72 + sc + 8] = v1;
        }
        __syncthreads();

        // ---- S = Q K^T / 8 ----
        f32x4 s[4];
#pragma unroll
        for (int n = 0; n < 4; ++n) {
            s[n] = (f32x4){0.f, 0.f, 0.f, 0.f};
            short8 bk0 = *(const short8*)&Ks[(n * 16 + lr) * 72 + lg * 8];
            short8 bk1 = *(const short8*)&Ks[(n * 16 + lr) * 72 + 32 + lg * 8];
            s[n] = mfma_bf16(aq0, bk0, s[n]);
            s[n] = mfma_bf16(aq1, bk1, s[n]);
        }
#pragma unroll
        for (int n = 0; n < 4; ++n)
#pragma unroll
            for (int r = 0; r < 4; ++r) s[n][r] *= 0.125f;

        // ---- online softmax (row = lg*4+r; 16 cols spread over lr lanes) ----
        float mnew[4], alpha[4];
#pragma unroll
        for (int r = 0; r < 4; ++r) {
            float rm = fmaxf(fmaxf(s[0][r], s[1][r]), fmaxf(s[2][r], s[3][r]));
            rm = fmaxf(rm, __shfl_xor(rm, 1));
            rm = fmaxf(rm, __shfl_xor(rm, 2));
            rm = fmaxf(rm, __shfl_xor(rm, 4));
            rm = fmaxf(rm, __shfl_xor(rm, 8));
            mnew[r] = fmaxf(ms[r], rm);
            alpha[r] = __expf(ms[r] - mnew[r]);
            ms[r] = mnew[r];
        }
        float p[4][4];
#pragma unroll
        for (int r = 0; r < 4; ++r) {
            float rs = 0.f;
#pragma unroll
            for (int n = 0; n < 4; ++n) { p[n][r] = __expf(s[n][r] - mnew[r]); rs += p[n][r]; }
            rs += __shfl_xor(rs, 1);
            rs += __shfl_xor(rs, 2);
            rs += __shfl_xor(rs, 4);
            rs += __shfl_xor(rs, 8);
            ls[r] = ls[r] * alpha[r] + rs;
        }
#pragma unroll
        for (int n = 0; n < 4; ++n)
#pragma unroll
            for (int r = 0; r < 4; ++r) accx[n][r] *= alpha[r];

        // ---- P -> LDS (bf16), then PV ----
#pragma unroll
        for (int r = 0; r < 4; ++r)
#pragma unroll
            for (int n = 0; n < 4; ++n)
                pw[(lg * 4 + r) * 72 + n * 16 + lr] = f2bf(p[n][r]);
        __syncthreads();
#pragma unroll
        for (int ks = 0; ks < 2; ++ks) {
            short8 ap = *(const short8*)&pw[lr * 72 + ks * 32 + lg * 8];
#pragma unroll
            for (int nd = 0; nd < 4; ++nd) {
                short8 bv = *(const short8*)&Vs[(nd * 16 + lr) * 72 + ks * 32 + lg * 8];
                accx[nd] = mfma_bf16(ap, bv, accx[nd]);
            }
        }
        __syncthreads();
    }

    // ---- epilogue: normalize by l, write bf16 x_buf [2048][1024] ----
    const int b = bh >> 4, h = bh & 15;
#pragma unroll
    for (int r = 0; r < 4; ++r) {
        float inv = 1.0f / ls[r];
        int m = b * 1024 + qt * 64 + w * 16 + lg * 4 + r;
#pragma unroll
        for (int nd = 0; nd < 4; ++nd) {
            int c = h * 64 + nd * 16 + lr;
            xb[(size_t)m * NFEAT + c] = f2bf(accx[nd][r] * inv);
        }
    }
}

// ---------------------------------------------------------------------------
extern "C" void kernel_launch(void* const* d_in, const int* in_sizes, int n_in,
                              void* d_out, int out_size, void* d_ws, size_t ws_size,
                              hipStream_t stream) {
    const float* query = (const float*)d_in[0];
    const float* key   = (const float*)d_in[1];
    const float* value = (const float*)d_in[2];
    const float* cache = (const float*)d_in[3];
    const float* Wq = (const float*)d_in[4];
    const float* bq = (const float*)d_in[5];
    const float* Wk = (const float*)d_in[6];
    const float* bk = (const float*)d_in[7];
    const float* Wv = (const float*)d_in[8];
    const float* bv = (const float*)d_in[9];
    const float* Wo = (const float*)d_in[10];
    const float* bo = (const float*)d_in[11];

    float* out0   = (float*)d_out;                        // [2,1024,1024]
    float* ncache = out0 + (size_t)2 * 1024 * 1024;       // [2,16,2048,128]

    short* qbuf = (short*)d_ws;                           // [BH,1024,64]  4MB
    short* kbb  = qbuf + (size_t)2 * 16 * 1024 * 64;      // [BH,2048,64]  8MB
    short* vtb  = kbb  + (size_t)2 * 16 * 2048 * 64;      // [BH,64,2048]  8MB
    short* xb   = vtb  + (size_t)2 * 16 * 64 * 2048;      // [2048,1024]   4MB

    cache_prep<<<4096, 256, 0, stream>>>((const float4*)cache, (float4*)ncache, kbb, vtb);

    dim3 g(NFEAT / 64, 2048 / 64);
    gemm_bt<1, false><<<g, 256, 0, stream>>>(query, Wq, bq, nullptr, qbuf, nullptr, 2048, NFEAT, NFEAT);
    gemm_bt<2, false><<<g, 256, 0, stream>>>(key,   Wk, bk, ncache,  kbb,  nullptr, 2048, NFEAT, NFEAT);
    gemm_bt<3, false><<<g, 256, 0, stream>>>(value, Wv, bv, ncache,  nullptr, vtb,  2048, NFEAT, NFEAT);

    attn_kernel<<<512, 256, 0, stream>>>(qbuf, kbb, vtb, xb);

    gemm_bt<0, true><<<g, 256, 0, stream>>>(xb, Wo, bo, out0, nullptr, nullptr, 2048, NFEAT, NFEAT);
}

// Round 2
// 159.313 us; speedup vs baseline: 1.3585x; 1.3585x over previous
//
#include <hip/hip_runtime.h>

typedef short short4s __attribute__((ext_vector_type(4)));
typedef short short8 __attribute__((ext_vector_type(8)));
typedef __bf16 bf16x8 __attribute__((ext_vector_type(8)));
typedef float f32x4 __attribute__((ext_vector_type(4)));

#define NFEAT 1024
#define HDIM  64
#define NHEAD 16
#define TC2   2048
#define QSCL  0.18033688011112043f   // log2(e)/8 folded into Q

__device__ __forceinline__ short f2bf(float f) {
    unsigned int u = __builtin_bit_cast(unsigned int, f);
    u += 0x7fffu + ((u >> 16) & 1u);
    return (short)(u >> 16);
}

__device__ __forceinline__ f32x4 mfma_bf16(short8 a, short8 b, f32x4 c) {
    return __builtin_amdgcn_mfma_f32_16x16x32_bf16(
        __builtin_bit_cast(bf16x8, a), __builtin_bit_cast(bf16x8, b), c, 0, 0, 0);
}

#define GLOAD16(gp, lp) __builtin_amdgcn_global_load_lds( \
    (const __attribute__((address_space(1))) void*)(gp),  \
    (__attribute__((address_space(3))) void*)(lp), 16, 0, 0)

// ---------------------------------------------------------------------------
// prep: fp32->bf16 conversion of q/k/v inputs + 4 weight matrices, plus the
// cache copy (fp32 passthrough) + bf16 K / V^T side buffers.
// blocks 0..5119: conversions (2048 elems/block). 5120..9215: cache.
// ---------------------------------------------------------------------------
__global__ __launch_bounds__(256) void prep_kernel(
    const float* __restrict__ q, const float* __restrict__ k, const float* __restrict__ v,
    const float* __restrict__ Wq, const float* __restrict__ Wk,
    const float* __restrict__ Wv, const float* __restrict__ Wo,
    const float4* __restrict__ cache4,
    short* __restrict__ qin, short* __restrict__ kin, short* __restrict__ vin,
    short* __restrict__ wqb, short* __restrict__ wkb, short* __restrict__ wvb,
    short* __restrict__ wob,
    float4* __restrict__ nc4, short* __restrict__ kbb, short* __restrict__ vtb)
{
    const int b = blockIdx.x, tid = threadIdx.x;
    if (b < 5120) {
        const float* src; short* dst; size_t base;
        if (b < 1024)      { src = q;  dst = qin; base = (size_t)b * 2048; }
        else if (b < 2048) { src = k;  dst = kin; base = (size_t)(b - 1024) * 2048; }
        else if (b < 3072) { src = v;  dst = vin; base = (size_t)(b - 2048) * 2048; }
        else if (b < 3584) { src = Wq; dst = wqb; base = (size_t)(b - 3072) * 2048; }
        else if (b < 4096) { src = Wk; dst = wkb; base = (size_t)(b - 3584) * 2048; }
        else if (b < 4608) { src = Wv; dst = wvb; base = (size_t)(b - 4096) * 2048; }
        else               { src = Wo; dst = wob; base = (size_t)(b - 4608) * 2048; }
        size_t i = base + (size_t)tid * 8;
        float4 a0 = *(const float4*)(src + i);
        float4 a1 = *(const float4*)(src + i + 4);
        short8 o;
        o[0] = f2bf(a0.x); o[1] = f2bf(a0.y); o[2] = f2bf(a0.z); o[3] = f2bf(a0.w);
        o[4] = f2bf(a1.x); o[5] = f2bf(a1.y); o[6] = f2bf(a1.z); o[7] = f2bf(a1.w);
        *(short8*)(dst + i) = o;
    } else {
        int i = (b - 5120) * 256 + tid;           // over 2*16*1024*32 float4
        int c4 = i & 31;
        int t  = (i >> 5) & 1023;
        int bh = i >> 15;
        float4 val = cache4[i];
        nc4[((size_t)bh * TC2 + t) * 32 + c4] = val;
        int c = c4 * 4;
        if (c < 64) {
            size_t base = ((size_t)bh * TC2 + t) * HDIM + c;
            kbb[base + 0] = f2bf(val.x); kbb[base + 1] = f2bf(val.y);
            kbb[base + 2] = f2bf(val.z); kbb[base + 3] = f2bf(val.w);
        } else {
            int d = c - 64;
            size_t base = ((size_t)bh * HDIM + d) * TC2 + t;
            vtb[base + 0 * TC2] = f2bf(val.x); vtb[base + 1 * TC2] = f2bf(val.y);
            vtb[base + 2 * TC2] = f2bf(val.z); vtb[base + 3 * TC2] = f2bf(val.w);
        }
    }
}

// ---------------------------------------------------------------------------
// 128x128 GEMM, BK=64, global_load_lds staging (m97 structure).
// y[m][n] = sum_k A[m][k]*W[n][k] + bias[n].  M=2048, N=K=1024.
// mode 0=Q 1=K 2=V (selected by blockIdx.z), base_mode==3 -> O projection.
// ---------------------------------------------------------------------------
__global__ __launch_bounds__(256) void gemm128(
    const short* __restrict__ A0, const short* __restrict__ A1, const short* __restrict__ A2,
    const short* __restrict__ W0, const short* __restrict__ W1, const short* __restrict__ W2,
    const float* __restrict__ b0, const float* __restrict__ b1, const float* __restrict__ b2,
    float* __restrict__ outf, short* __restrict__ qbuf,
    short* __restrict__ kbb, short* __restrict__ vtb, int base_mode)
{
    __shared__ short As[128 * 64];
    __shared__ short Bs[128 * 64];

    int mode;
    const short *A, *W;
    const float* bias;
    if (base_mode == 3) { mode = 3; A = A0; W = W0; bias = b0; }
    else {
        mode = blockIdx.z;
        if (mode == 0)      { A = A0; W = W0; bias = b0; }
        else if (mode == 1) { A = A1; W = W1; bias = b1; }
        else                { A = A2; W = W2; bias = b2; }
    }

    const int tid = threadIdx.x, lane = tid & 63, w = tid >> 6;
    const int wr = w >> 1, wc = w & 1;
    const int lr = lane & 15, lg = lane >> 4;
    const int bx = blockIdx.x, by = blockIdx.y;

    f32x4 acc[4][4];
#pragma unroll
    for (int m = 0; m < 4; ++m)
#pragma unroll
        for (int n = 0; n < 4; ++n) acc[m][n] = (f32x4){0.f, 0.f, 0.f, 0.f};

    const short* agBase = A + (size_t)(by * 128 + w * 32 + (lane >> 3)) * 1024 + (lane & 7) * 8;
    const short* bgBase = W + (size_t)(bx * 128 + w * 32 + (lane >> 3)) * 1024 + (lane & 7) * 8;
    short* asW = &As[w * 2048];
    short* bsW = &Bs[w * 2048];

    for (int kt = 0; kt < 16; ++kt) {
        const short* ag = agBase + kt * 64;
        const short* bg = bgBase + kt * 64;
        GLOAD16(ag,          asW);
        GLOAD16(ag + 8192,   asW + 512);
        GLOAD16(ag + 16384,  asW + 1024);
        GLOAD16(ag + 24576,  asW + 1536);
        GLOAD16(bg,          bsW);
        GLOAD16(bg + 8192,   bsW + 512);
        GLOAD16(bg + 16384,  bsW + 1024);
        GLOAD16(bg + 24576,  bsW + 1536);
        __syncthreads();
#pragma unroll
        for (int kk = 0; kk < 2; ++kk) {
            short8 af[4], bf[4];
#pragma unroll
            for (int m = 0; m < 4; ++m)
                af[m] = *(const short8*)&As[(wr * 64 + m * 16 + lr) * 64 + kk * 32 + lg * 8];
#pragma unroll
            for (int n = 0; n < 4; ++n)
                bf[n] = *(const short8*)&Bs[(wc * 64 + n * 16 + lr) * 64 + kk * 32 + lg * 8];
#pragma unroll
            for (int m = 0; m < 4; ++m)
#pragma unroll
                for (int n = 0; n < 4; ++n)
                    acc[m][n] = mfma_bf16(af[m], bf[n], acc[m][n]);
        }
        __syncthreads();
    }

    // ---- epilogue ----
#pragma unroll
    for (int m = 0; m < 4; ++m) {
#pragma unroll
        for (int n = 0; n < 4; ++n) {
            const int cg = bx * 128 + wc * 64 + n * 16 + lr;
            const int rg0 = by * 128 + wr * 64 + m * 16 + lg * 4;
            const float bv = bias[cg];
            if (mode == 3) {
#pragma unroll
                for (int r = 0; r < 4; ++r)
                    outf[(size_t)(rg0 + r) * NFEAT + cg] = acc[m][n][r] + bv;
            } else {
                const int b = rg0 >> 10, t0 = rg0 & 1023;
                const int h = cg >> 6, d = cg & 63;
                const size_t bh = (size_t)b * NHEAD + h;
                if (mode == 0) {
#pragma unroll
                    for (int r = 0; r < 4; ++r)
                        qbuf[(bh * 1024 + t0 + r) * HDIM + d] = f2bf((acc[m][n][r] + bv) * QSCL);
                } else if (mode == 1) {
#pragma unroll
                    for (int r = 0; r < 4; ++r) {
                        float val = acc[m][n][r] + bv;
                        outf[(bh * TC2 + 1024 + t0 + r) * 128 + d] = val;
                        kbb[(bh * TC2 + 1024 + t0 + r) * HDIM + d] = f2bf(val);
                    }
                } else {
                    short4s pk;
#pragma unroll
                    for (int r = 0; r < 4; ++r) {
                        float val = acc[m][n][r] + bv;
                        outf[(bh * TC2 + 1024 + t0 + r) * 128 + 64 + d] = val;
                        pk[r] = f2bf(val);
                    }
                    *(short4s*)&vtb[(bh * HDIM + d) * TC2 + 1024 + t0] = pk;
                }
            }
        }
    }
}

// ---------------------------------------------------------------------------
// Flash attention. Block = (bh, q-tile of 64) with XCD-affinity swizzle so the
// 16 q-tiles of a head stay on one XCD (KV working set 512KB << 4MB L2).
// Reg-staged K/V (T14 async split), exp2 softmax (Q pre-scaled), one barrier
// saved via wave-local P handoff.
// ---------------------------------------------------------------------------
#define PSS 76
__global__ __launch_bounds__(256) void attn_kernel(
    const short* __restrict__ qb, const short* __restrict__ kb,
    const short* __restrict__ vtb, short* __restrict__ xb)
{
    __shared__ short Ks[64 * 72];
    __shared__ short Vs[64 * 72];
    __shared__ short Ps[4 * 16 * PSS];

    const int tid = threadIdx.x, lane = tid & 63, w = tid >> 6;
    const int lr = lane & 15, lg = lane >> 4;
    const int b0 = blockIdx.x;
    const int xcd = b0 & 7, slot = b0 >> 3;
    const int bh = xcd + 8 * (slot & 3);
    const int qt = slot >> 2;

    const short* qrow = qb + ((size_t)bh * 1024 + qt * 64 + w * 16 + lr) * HDIM;
    const short8 aq0 = *(const short8*)(qrow + lg * 8);
    const short8 aq1 = *(const short8*)(qrow + 32 + lg * 8);

    f32x4 accx[4];
#pragma unroll
    for (int i = 0; i < 4; ++i) accx[i] = (f32x4){0.f, 0.f, 0.f, 0.f};
    float ms[4], ls[4];
#pragma unroll
    for (int r = 0; r < 4; ++r) { ms[r] = -3.0e38f; ls[r] = 0.f; }

    const int srow = tid >> 2, sc = (tid & 3) * 16;
    short* pw = &Ps[w * 16 * PSS];

    const short* kg = kb + ((size_t)bh * TC2 + srow) * HDIM + sc;     // +kvt*64*HDIM
    const short* vg = vtb + ((size_t)bh * HDIM + srow) * TC2 + sc;    // +kvt*64

    short8 kr0 = *(const short8*)kg;
    short8 kr1 = *(const short8*)(kg + 8);
    short8 vr0 = *(const short8*)vg;
    short8 vr1 = *(const short8*)(vg + 8);

    for (int kvt = 0; kvt < TC2 / 64; ++kvt) {
        __syncthreads();                                   // prev tile reads done
        *(short8*)&Ks[srow * 72 + sc]     = kr0;
        *(short8*)&Ks[srow * 72 + sc + 8] = kr1;
        *(short8*)&Vs[srow * 72 + sc]     = vr0;
        *(short8*)&Vs[srow * 72 + sc + 8] = vr1;
        __syncthreads();                                   // LDS ready
        if (kvt + 1 < TC2 / 64) {                          // async prefetch next tile
            const short* kn = kg + (size_t)(kvt + 1) * 64 * HDIM;
            const short* vn = vg + (size_t)(kvt + 1) * 64;
            kr0 = *(const short8*)kn;
            kr1 = *(const short8*)(kn + 8);
            vr0 = *(const short8*)vn;
            vr1 = *(const short8*)(vn + 8);
        }

        // ---- S' = (Q*log2e/8) K^T ----
        f32x4 s[4];
#pragma unroll
        for (int n = 0; n < 4; ++n) {
            s[n] = (f32x4){0.f, 0.f, 0.f, 0.f};
            short8 bk0 = *(const short8*)&Ks[(n * 16 + lr) * 72 + lg * 8];
            short8 bk1 = *(const short8*)&Ks[(n * 16 + lr) * 72 + 32 + lg * 8];
            s[n] = mfma_bf16(aq0, bk0, s[n]);
            s[n] = mfma_bf16(aq1, bk1, s[n]);
        }

        // ---- online softmax in exp2 domain ----
        float mnew[4], alpha[4];
#pragma unroll
        for (int r = 0; r < 4; ++r) {
            float rm = fmaxf(fmaxf(s[0][r], s[1][r]), fmaxf(s[2][r], s[3][r]));
            rm = fmaxf(rm, __shfl_xor(rm, 1));
            rm = fmaxf(rm, __shfl_xor(rm, 2));
            rm = fmaxf(rm, __shfl_xor(rm, 4));
            rm = fmaxf(rm, __shfl_xor(rm, 8));
            mnew[r] = fmaxf(ms[r], rm);
            alpha[r] = __builtin_amdgcn_exp2f(ms[r] - mnew[r]);
            ms[r] = mnew[r];
        }
        float p[4][4];
#pragma unroll
        for (int r = 0; r < 4; ++r) {
            float rs = 0.f;
#pragma unroll
            for (int n = 0; n < 4; ++n) {
                p[n][r] = __builtin_amdgcn_exp2f(s[n][r] - mnew[r]);
                rs += p[n][r];
            }
            rs += __shfl_xor(rs, 1);
            rs += __shfl_xor(rs, 2);
            rs += __shfl_xor(rs, 4);
            rs += __shfl_xor(rs, 8);
            ls[r] = ls[r] * alpha[r] + rs;
        }
#pragma unroll
        for (int n = 0; n < 4; ++n)
#pragma unroll
            for (int r = 0; r < 4; ++r) accx[n][r] *= alpha[r];

        // ---- P -> LDS (wave-private region; no block barrier needed) ----
#pragma unroll
        for (int r = 0; r < 4; ++r)
#pragma unroll
            for (int n = 0; n < 4; ++n)
                pw[(lg * 4 + r) * PSS + n * 16 + lr] = f2bf(p[n][r]);
        asm volatile("s_waitcnt lgkmcnt(0)" ::: "memory");
        __builtin_amdgcn_sched_barrier(0);

        // ---- PV ----
#pragma unroll
        for (int ks = 0; ks < 2; ++ks) {
            short8 ap = *(const short8*)&pw[lr * PSS + ks * 32 + lg * 8];
#pragma unroll
            for (int nd = 0; nd < 4; ++nd) {
                short8 bv = *(const short8*)&Vs[(nd * 16 + lr) * 72 + ks * 32 + lg * 8];
                accx[nd] = mfma_bf16(ap, bv, accx[nd]);
            }
        }
    }

    const int b = bh >> 4, h = bh & 15;
#pragma unroll
    for (int r = 0; r < 4; ++r) {
        float inv = 1.0f / ls[r];
        int m = b * 1024 + qt * 64 + w * 16 + lg * 4 + r;
#pragma unroll
        for (int nd = 0; nd < 4; ++nd) {
            int c = h * 64 + nd * 16 + lr;
            xb[(size_t)m * NFEAT + c] = f2bf(accx[nd][r] * inv);
        }
    }
}

// ---------------------------------------------------------------------------
extern "C" void kernel_launch(void* const* d_in, const int* in_sizes, int n_in,
                              void* d_out, int out_size, void* d_ws, size_t ws_size,
                              hipStream_t stream) {
    const float* query = (const float*)d_in[0];
    const float* key   = (const float*)d_in[1];
    const float* value = (const float*)d_in[2];
    const float* cache = (const float*)d_in[3];
    const float* Wq = (const float*)d_in[4];
    const float* bq = (const float*)d_in[5];
    const float* Wk = (const float*)d_in[6];
    const float* bk = (const float*)d_in[7];
    const float* Wv = (const float*)d_in[8];
    const float* bv = (const float*)d_in[9];
    const float* Wo = (const float*)d_in[10];
    const float* bo = (const float*)d_in[11];

    float* out0   = (float*)d_out;
    float* ncache = out0 + (size_t)2 * 1024 * 1024;

    short* qin = (short*)d_ws;                       // [2048][1024] bf16
    short* kin = qin + (size_t)2048 * 1024;
    short* vin = kin + (size_t)2048 * 1024;
    short* wqb = vin + (size_t)2048 * 1024;          // [1024][1024] bf16 x4
    short* wkb = wqb + (size_t)1024 * 1024;
    short* wvb = wkb + (size_t)1024 * 1024;
    short* wob = wvb + (size_t)1024 * 1024;
    short* qbuf = wob + (size_t)1024 * 1024;         // [32][1024][64]
    short* kbb  = qbuf + (size_t)32 * 1024 * 64;     // [32][2048][64]
    short* vtb  = kbb  + (size_t)32 * 2048 * 64;     // [32][64][2048]
    short* xb   = qin;                               // alias (qin dead after QKV gemm)

    prep_kernel<<<9216, 256, 0, stream>>>(query, key, value, Wq, Wk, Wv, Wo,
        (const float4*)cache, qin, kin, vin, wqb, wkb, wvb, wob,
        (float4*)ncache, kbb, vtb);

    gemm128<<<dim3(8, 16, 3), 256, 0, stream>>>(qin, kin, vin, wqb, wkb, wvb,
        bq, bk, bv, ncache, qbuf, kbb, vtb, 0);

    attn_kernel<<<512, 256, 0, stream>>>(qbuf, kbb, vtb, xb);

    gemm128<<<dim3(8, 16, 1), 256, 0, stream>>>(xb, nullptr, nullptr, wob, nullptr, nullptr,
        bo, nullptr, nullptr, out0, nullptr, nullptr, nullptr, 3);
}